// Round 11
// baseline (527.772 us; speedup 1.0000x reference)
//
#include <hip/hip_runtime.h>
#include <math.h>

#define HW 9216
#define CIN 256
#define COUT 256

typedef _Float16 f16;
typedef _Float16 half8 __attribute__((ext_vector_type(8)));
typedef float f32x4 __attribute__((ext_vector_type(4)));
typedef unsigned int u32x4 __attribute__((ext_vector_type(4)));  // native vec for nt-store

struct F2 { float a, b; };

// XCD-locality swizzle (8 XCDs, blockIdx round-robins XCDs via bx&7).
__device__ __forceinline__ void swz576(int bx, int& b, int& tile) {
    int xcd = bx & 7, k = bx >> 3;      // k in [0,72)
    b = xcd >> 1;
    tile = (xcd & 1) * 72 + k;
}

// ---------------- K0a: x NCHW f32 -> xt NHWC f16 ----------------
__global__ __launch_bounds__(256) void k_prep_x(const float* __restrict__ x,
                                                f16* __restrict__ xt) {
    __shared__ f16 tile[64][256];
    int b, tl; swz576(blockIdx.x, b, tl);
    int pxb = tl * 64;
    int t = threadIdx.x;
    int cq = t >> 2, q = t & 3;
    for (int cp = 0; cp < 4; ++cp) {
        int c = cp * 64 + cq;
        const float* src = x + ((size_t)(b * 256 + c)) * HW + pxb + q * 16;
#pragma unroll
        for (int ii = 0; ii < 4; ++ii) {
            float4 v = *(const float4*)(src + ii * 4);
            int p0 = q * 16 + ii * 4;
            tile[p0 + 0][c] = (f16)v.x; tile[p0 + 1][c] = (f16)v.y;
            tile[p0 + 2][c] = (f16)v.z; tile[p0 + 3][c] = (f16)v.w;
        }
    }
    __syncthreads();
    int cg = t & 31, ph = t >> 5;
#pragma unroll
    for (int it = 0; it < 8; ++it) {
        int px = it * 8 + ph;
        *(uint4*)(xt + ((size_t)(b * HW + pxb + px)) * 256 + cg * 8) =
            *(const uint4*)&tile[px][cg * 8];
    }
}

// ---------------- K0b: w_dcn -> wt2 f16, frag-major (proven r6) ----------------
__global__ __launch_bounds__(256) void k_prep_w(const float* __restrict__ w_dcn,
                                                f16* __restrict__ wt2) {
    int gid = blockIdx.x * 256 + threadIdx.x;   // < 589824
    int e = gid & 7;
    int cout = (gid >> 3) & 255;
    int r2 = gid >> 11;
    int g = r2 & 3, kb = (r2 >> 2) & 7, tap = r2 >> 5;
    int cin = kb * 32 + ((e >> 2) << 4) + (g << 2) + (e & 3);
    wt2[gid] = (f16)w_dcn[((size_t)cout * 256 + cin) * 9 + tap];
}

// ---------------- K0c: w_off -> w_offp [(o*9+tap)*256 + cin] f32 ----------------
__global__ __launch_bounds__(256) void k_prep_wo(const float* __restrict__ w_off,
                                                 float* __restrict__ w_offp) {
    int gid = blockIdx.x * 256 + threadIdx.x;   // 41472 exact
    int cin = gid & 255;
    int r = gid >> 8;                           // o*9+tap
    int tap = r % 9, o = r / 9;
    w_offp[gid] = w_off[((size_t)o * 256 + cin) * 9 + tap];
}

// ---------------- K1: offsets conv 256->18, reads xt NHWC f16 ----------------
__global__ __launch_bounds__(512) void k_off(const f16* __restrict__ xt,
                                             const float* __restrict__ w_offp,
                                             const float* __restrict__ b_off,
                                             f16* __restrict__ off) {
    __shared__ float red[8][64][19];
    int b, tl; swz576(blockIdx.x, b, tl);
    int t = threadIdx.x;
    int px = t & 63;
    int cpart = __builtin_amdgcn_readfirstlane(t >> 6);  // force SGPR
    int pxf = tl * 64 + px;
    int h = pxf / 96, w = pxf - h * 96;
    const char* xb = (const char*)(xt + (size_t)b * HW * 256);

    float acc[18];
#pragma unroll
    for (int o = 0; o < 18; ++o) acc[o] = 0.f;

    for (int tap = 0; tap < 9; ++tap) {
        int dy = tap / 3 - 1, dx = tap - (tap / 3) * 3 - 1;
        int h2 = h + dy, w2 = w + dx;
        bool ok = ((unsigned)h2 < 96u) && ((unsigned)w2 < 96u);
        int src = ok ? h2 * 96 + w2 : 0;
        const char* xp = xb + (size_t)src * 512;
#pragma unroll
        for (int mi = 0; mi < 4; ++mi) {
            int mm = cpart * 4 + mi;
            uint4 raw = *(const uint4*)(xp + mm * 16);
            const f16* hx = (const f16*)&raw;
            float xv[8];
#pragma unroll
            for (int e = 0; e < 8; ++e) xv[e] = ok ? (float)hx[e] : 0.f;
            const float* wb = w_offp + mm * 8;
#pragma unroll
            for (int o = 0; o < 18; ++o) {
                const float* wp = wb + (o * 9 + tap) * 256;   // SGPR-uniform
#pragma unroll
                for (int e = 0; e < 8; ++e) acc[o] += wp[e] * xv[e];
            }
        }
    }
#pragma unroll
    for (int o = 0; o < 18; ++o) red[cpart][px][o] = acc[o];
    __syncthreads();
    if (t < 64) {
        float s[18];
#pragma unroll
        for (int o = 0; o < 18; ++o) s[o] = b_off[o];
        for (int cp = 0; cp < 8; ++cp)
#pragma unroll
            for (int o = 0; o < 18; ++o) s[o] += red[cp][t][o];
#pragma unroll
        for (int o = 0; o < 18; ++o)
            off[((size_t)(b * 18 + o)) * HW + tl * 64 + t] = (f16)s[o];
    }
}

// ---------------- K2: deformable conv, fp16 MFMA + T14 tap prefetch ----------------
// 512 thr = 8 waves. Tap t+1's 16 corner uint4s issued before tap t's barriers:
// in flight across LDS-write + MFMA phase. VGPR ~120 -> 2 blocks/CU (launch_bounds 4).
__global__ __launch_bounds__(512, 4) void k_dcn(const f16* __restrict__ xt,
                                                const f16* __restrict__ off,
                                                const f16* __restrict__ wt2,
                                                const float* __restrict__ b_dcn,
                                                f16* __restrict__ y,
                                                float* __restrict__ gsum,
                                                float* __restrict__ gss) {
    __shared__ uint4  A4[2048];     // 32KB  A[64px][256cin] f16, frag-permuted + XOR swz
    __shared__ int4   idx4[576];    // [tap][px] corner BYTE offsets
    __shared__ float4 wt4[576];     // [tap][px] bilinear weights

    int b, tile; swz576(blockIdx.x, b, tile);
    int pxb = tile * 64;
    int t = threadIdx.x;
    int lane = t & 63, wv = t >> 6;

    // ---- Phase A: bilinear tables ----
    for (int e = t; e < 576; e += 512) {
        int p = e & 63, tap = e >> 6;
        int pxf = pxb + p;
        int h = pxf / 96, w = pxf - h * 96;
        const f16* ob = off + (size_t)b * 18 * HW + pxf;
        float oy = (float)ob[(size_t)(2 * tap) * HW];
        float ox = (float)ob[(size_t)(2 * tap + 1) * HW];
        float py  = (float)(h + tap / 3 - 1) + oy;
        float pxx = (float)(w + tap % 3 - 1) + ox;
        float y0f = floorf(py), x0f = floorf(pxx);
        float wy = py - y0f, wx = pxx - x0f;
        int yi0 = (int)y0f, xi0 = (int)x0f;
        int yi1 = yi0 + 1, xi1 = xi0 + 1;
        bool vy0 = (unsigned)yi0 < 96u, vy1 = (unsigned)yi1 < 96u;
        bool vx0 = (unsigned)xi0 < 96u, vx1 = (unsigned)xi1 < 96u;
        int cy0 = min(max(yi0, 0), 95), cy1 = min(max(yi1, 0), 95);
        int cx0 = min(max(xi0, 0), 95), cx1 = min(max(xi1, 0), 95);
        idx4[e] = make_int4((cy0 * 96 + cx0) * 512, (cy0 * 96 + cx1) * 512,
                            (cy1 * 96 + cx0) * 512, (cy1 * 96 + cx1) * 512);
        wt4[e] = make_float4((vy0 && vx0) ? (1.f - wy) * (1.f - wx) : 0.f,
                             (vy0 && vx1) ? (1.f - wy) * wx : 0.f,
                             (vy1 && vx0) ? wy * (1.f - wx) : 0.f,
                             (vy1 && vx1) ? wy * wx : 0.f);
    }

    int g = lane >> 4, l15 = lane & 15;
    const char* xtb = (const char*)(xt + (size_t)b * HW * 256);

    f32x4 acc[4][2];
#pragma unroll
    for (int R = 0; R < 4; ++R) {
        acc[R][0] = (f32x4){0.f, 0.f, 0.f, 0.f};
        acc[R][1] = (f32x4){0.f, 0.f, 0.f, 0.f};
    }

    int m = lane & 31;              // cin chunk (16B)
    int phl = lane >> 5;            // pixel-pair member
    int qq = m & 3;
    int preA_base = (m >> 2) * 64 + (qq & 1) * 32 + ((qq & 2) ? 8 : 0);
    int cout0 = wv * 32 + l15;

    uint4 pf[4][4];                 // prefetched corners [round][corner]
    auto issue_tap = [&](int tp) {
#pragma unroll
        for (int rr = 0; rr < 4; ++rr) {
            int p = wv * 8 + rr * 2 + phl;
            int4 id = idx4[tp * 64 + p];
            pf[rr][0] = *(const uint4*)(xtb + id.x + m * 16);
            pf[rr][1] = *(const uint4*)(xtb + id.y + m * 16);
            pf[rr][2] = *(const uint4*)(xtb + id.z + m * 16);
            pf[rr][3] = *(const uint4*)(xtb + id.w + m * 16);
        }
    };

    __syncthreads();                // Phase A tables ready
    issue_tap(0);

#pragma unroll
    for (int tap = 0; tap < 9; ++tap) {
        // ---- combine prefetched corners (waits vmcnt here; loads long in flight) ----
        uint2 cmb[4][2];
#pragma unroll
        for (int rr = 0; rr < 4; ++rr) {
            int p = wv * 8 + rr * 2 + phl;
            float4 wgt = wt4[tap * 64 + p];
            const f16* a0 = (const f16*)&pf[rr][0];
            const f16* a1 = (const f16*)&pf[rr][1];
            const f16* a2 = (const f16*)&pf[rr][2];
            const f16* a3 = (const f16*)&pf[rr][3];
            union { f16 h[8]; uint2 u2[2]; } pu;
#pragma unroll
            for (int ii = 0; ii < 8; ++ii) {
                float s = wgt.x * (float)a0[ii] + wgt.y * (float)a1[ii]
                        + wgt.z * (float)a2[ii] + wgt.w * (float)a3[ii];
                pu.h[ii] = (f16)s;
            }
            cmb[rr][0] = pu.u2[0];
            cmb[rr][1] = pu.u2[1];
        }
        if (tap < 8) issue_tap(tap + 1);   // pf dead -> refill for next tap

        __syncthreads();            // A4 free (MFMA of tap-1 done reading)
#pragma unroll
        for (int rr = 0; rr < 4; ++rr) {
            int p = wv * 8 + rr * 2 + phl;
            int preA = p * 512 + preA_base;
            int swz = (p & 7) << 4;
            *(uint2*)((char*)A4 + ((preA) ^ swz))      = cmb[rr][0];
            *(uint2*)((char*)A4 + ((preA + 16) ^ swz)) = cmb[rr][1];
        }
        __syncthreads();            // A4 ready

        // ---- MFMA: 8 K-steps of 32 ----
#pragma unroll
        for (int kb = 0; kb < 8; ++kb) {
            half8 Af[4];
#pragma unroll
            for (int R = 0; R < 4; ++R) {
                int byteA = ((R * 16 + l15) * 512 + kb * 64 + g * 16) ^ ((l15 & 7) << 4);
                Af[R] = *(const half8*)((const char*)A4 + byteA);
            }
#pragma unroll
            for (int nc = 0; nc < 2; ++nc) {
                const f16* bp = wt2 +
                    (((size_t)((tap * 8 + kb) * 4 + g) * 256 + cout0 + nc * 16) << 3);
                half8 Bf = *(const half8*)bp;
#pragma unroll
                for (int R = 0; R < 4; ++R)
                    acc[R][nc] = __builtin_amdgcn_mfma_f32_16x16x32_f16(Af[R], Bf, acc[R][nc], 0, 0, 0);
            }
        }
    }

    // ---- epilogue ----
    float bias0 = b_dcn[cout0], bias1 = b_dcn[cout0 + 16];
    float psum[2] = {0.f, 0.f}, pss[2] = {0.f, 0.f};
    __syncthreads();
    f16* ytile = (f16*)A4;          // [64 px][256 c]
#pragma unroll
    for (int R = 0; R < 4; ++R)
#pragma unroll
        for (int nc = 0; nc < 2; ++nc) {
            f32x4 v = acc[R][nc];
            float bb = nc ? bias1 : bias0;
            v.x += bb; v.y += bb; v.z += bb; v.w += bb;
            int cout = cout0 + nc * 16;
            int px0 = R * 16 + g * 4;
            ytile[(px0 + 0) * 256 + cout] = (f16)v.x;
            ytile[(px0 + 1) * 256 + cout] = (f16)v.y;
            ytile[(px0 + 2) * 256 + cout] = (f16)v.z;
            ytile[(px0 + 3) * 256 + cout] = (f16)v.w;
            psum[nc] += v.x + v.y + v.z + v.w;
            pss[nc]  += v.x * v.x + v.y * v.y + v.z * v.z + v.w * v.w;
        }
    __syncthreads();
    {
        const u32x4* src = (const u32x4*)A4;
        u32x4* dst = (u32x4*)(y + ((size_t)b * HW + pxb) * 256);
#pragma unroll
        for (int i = 0; i < 4; ++i)
            __builtin_nontemporal_store(src[i * 512 + t], &dst[i * 512 + t]);
    }
    __syncthreads();
    float4* red = (float4*)A4;
    red[t] = make_float4(psum[0], pss[0], psum[1], pss[1]);
    __syncthreads();
    if (t < 32) {
        float s = 0.f, ss = 0.f;
        int wv2 = t >> 2, nc = (t >> 1) & 1, h8 = t & 1;
        for (int g2 = 0; g2 < 4; ++g2)
#pragma unroll
            for (int i = 0; i < 8; ++i) {
                float4 r = red[wv2 * 64 + g2 * 16 + h8 * 8 + i];
                s  += nc ? r.z : r.x;
                ss += nc ? r.w : r.y;
            }
        gsum[((size_t)(b * 32 + t)) * 144 + tile] = s;
        gss [((size_t)(b * 32 + t)) * 144 + tile] = ss;
    }
}

// ---------------- K3: groupnorm stats -> ab + folded sig-conv weights ----------------
__global__ void k_stats(const float* __restrict__ gsum, const float* __restrict__ gss,
                        const float* __restrict__ gamma, const float* __restrict__ beta,
                        const float* __restrict__ w2,
                        F2* __restrict__ ab, float* __restrict__ w2s) {
    int t = blockIdx.x * 256 + threadIdx.x;
    if (t >= 1024) return;
    int b = t >> 8, c = t & 255, g = c >> 3;
    const float* ps = gsum + (size_t)(b * 32 + g) * 144;
    const float* pq = gss  + (size_t)(b * 32 + g) * 144;
    float s = 0.f, q = 0.f;
    for (int i = 0; i < 144; ++i) { s += ps[i]; q += pq[i]; }
    const float inv_n = 1.f / 73728.f;
    float mu = s * inv_n;
    float var = q * inv_n - mu * mu;
    float rstd = rsqrtf(var + 1e-5f);
    float A = rstd * gamma[c];
    float Bv = beta[c] - mu * A;
    ab[t].a = A;
    ab[t].b = Bv;
#pragma unroll
    for (int tap = 0; tap < 9; ++tap)
        w2s[((size_t)(b * 9 + tap)) * 256 + c] = A * w2[c * 9 + tap];
}

// ---------------- K3b: cB[b][tap] = sum_c Bv_c * w2[c][tap] (36 blocks, wave reduce) ----
__global__ void k_cb(const F2* __restrict__ ab, const float* __restrict__ w2,
                     float* __restrict__ cB) {
    int bt = blockIdx.x;                // 36 = b*9+tap
    int b = bt / 9, tap = bt - (bt / 9) * 9;
    int lane = threadIdx.x;             // 64
    float s = 0.f;
#pragma unroll
    for (int i = 0; i < 4; ++i) {
        int c = i * 64 + lane;
        s += ab[b * 256 + c].b * w2[c * 9 + tap];
    }
#pragma unroll
    for (int off = 32; off; off >>= 1) s += __shfl_down(s, off);
    if (lane == 0) cB[bt] = s;
}

// ---------------- K4: sigmoid gate, 32-px blocks + swizzle ----------------
__global__ __launch_bounds__(256) void k_sig(const f16* __restrict__ y,
                                             const float* __restrict__ w2s,
                                             const float* __restrict__ cB,
                                             const float* __restrict__ b2,
                                             float* __restrict__ sig) {
    __shared__ float red[256][4];
    int bx = blockIdx.x;                  // 1152 blocks
    int xcd = bx & 7, kk = bx >> 3;       // kk in [0,144)
    int b = xcd >> 1;
    int tile = (xcd & 1) * 72 + (kk >> 1);
    int pxb = tile * 64 + (kk & 1) * 32;
    int t = threadIdx.x;
    int m = t & 31, sub = t >> 5;
    const char* yb = (const char*)(y + (size_t)b * HW * 256);

    int hh[4], ww[4];
#pragma unroll
    for (int rr = 0; rr < 4; ++rr) {
        int pxf = pxb + rr * 8 + sub;
        hh[rr] = pxf / 96; ww[rr] = pxf - hh[rr] * 96;
    }
    float acc[4];
#pragma unroll
    for (int rr = 0; rr < 4; ++rr) acc[rr] = 0.f;

    for (int tap = 0; tap < 9; ++tap) {
        int dy = tap / 3 - 1, dx = tap - (tap / 3) * 3 - 1;
        const float* wp = w2s + ((size_t)(b * 9 + tap)) * 256 + m * 8;
        float wv0[8];
#pragma unroll
        for (int e = 0; e < 8; ++e) wv0[e] = wp[e];
        float cBt = cB[b * 9 + tap];
#pragma unroll
        for (int rr = 0; rr < 4; ++rr) {
            int h2 = hh[rr] + dy, w2i = ww[rr] + dx;
            bool ok = ((unsigned)h2 < 96u) && ((unsigned)w2i < 96u);
            int src = ok ? h2 * 96 + w2i : 0;
            uint4 raw = *(const uint4*)(yb + (size_t)src * 512 + m * 16);
            const f16* hx = (const f16*)&raw;
            float s = 0.f;
#pragma unroll
            for (int e = 0; e < 8; ++e) s += (float)hx[e] * wv0[e];
            s = ok ? s : 0.f;
            if (m == 0 && ok) s += cBt;
            acc[rr] += s;
        }
    }
#pragma unroll
    for (int rr = 0; rr < 4; ++rr) red[t][rr] = acc[rr];
    __syncthreads();
    if (t < 32) {
        int rr = t >> 3, sub2 = t & 7;
        float s = b2[0];
        for (int mm = 0; mm < 32; ++mm) s += red[sub2 * 32 + mm][rr];
        sig[(size_t)b * HW + pxb + rr * 8 + sub2] = 1.f / (1.f + expf(-s));
    }
}

// ---------------- K5: out = (y*A+B) * sig, NHWC->NCHW via LDS ----------------
__global__ __launch_bounds__(256) void k_final(const f16* __restrict__ y,
                                               const F2* __restrict__ ab,
                                               const float* __restrict__ sig,
                                               float* __restrict__ out) {
    __shared__ float tile_s[64 * 256];
    int b, tl; swz576(blockIdx.x, b, tl);
    int pxb = tl * 64;
    int t = threadIdx.x;
    int m = t & 31, sub = t >> 5;
    const char* yb = (const char*)(y + ((size_t)b * HW + pxb) * 256);
    float A[8], Bv[8];
    const F2* abp = ab + b * 256 + m * 8;
#pragma unroll
    for (int e = 0; e < 8; ++e) { A[e] = abp[e].a; Bv[e] = abp[e].b; }
#pragma unroll
    for (int rr = 0; rr < 8; ++rr) {
        int px = rr * 8 + sub;
        float sv = sig[(size_t)b * HW + pxb + px];
        uint4 raw = *(const uint4*)(yb + (size_t)px * 512 + m * 16);
        const f16* hx = (const f16*)&raw;
#pragma unroll
        for (int e = 0; e < 8; ++e)
            tile_s[px * 256 + m * 8 + e] = ((float)hx[e] * A[e] + Bv[e]) * sv;
    }
    __syncthreads();
#pragma unroll
    for (int r = 0; r < 16; ++r) {
        int c = r * 16 + (t >> 4);
        int q = t & 15;
        float4 v;
        v.x = tile_s[(q * 4 + 0) * 256 + c];
        v.y = tile_s[(q * 4 + 1) * 256 + c];
        v.z = tile_s[(q * 4 + 2) * 256 + c];
        v.w = tile_s[(q * 4 + 3) * 256 + c];
        *(float4*)(out + ((size_t)(b * 256 + c)) * HW + pxb + q * 4) = v;
    }
}

extern "C" void kernel_launch(void* const* d_in, const int* in_sizes, int n_in,
                              void* d_out, int out_size, void* d_ws, size_t ws_size,
                              hipStream_t stream) {
    (void)in_sizes; (void)n_in; (void)out_size; (void)ws_size;
    const float* x     = (const float*)d_in[0];
    const float* w_off = (const float*)d_in[1];
    const float* b_off = (const float*)d_in[2];
    const float* w_dcn = (const float*)d_in[3];
    const float* b_dcn = (const float*)d_in[4];
    const float* gamma = (const float*)d_in[5];
    const float* beta  = (const float*)d_in[6];
    const float* w2    = (const float*)d_in[7];
    const float* b2    = (const float*)d_in[8];
    float* out = (float*)d_out;

    char* p = (char*)d_ws;
    f16*   offp = (f16*)p;                        // 1,327,104
    f16*   y    = (f16*)(p + 1327104);            // 18,874,368  (NHWC)
    F2*    ab   = (F2*)(p + 20201472);            // 8,192
    char*  xtp  = p + 20209664;                   // 18,874,368
    f16*   xt   = (f16*)xtp;
    f16*   wt2  = (f16*)(p + 39084032);           // 1,179,648
    char*  wop  = p + 40263680;                   // 165,888
    float* w_offp = (float*)wop;
    // aliases (lifetime-disjoint, stream-serialized):
    float* gsum = (float*)wop;                    // after k_off done
    float* gss  = (float*)(wop + 73728);
    float* w2s  = (float*)xtp;                    // after k_dcn done
    float* cB   = (float*)(xtp + 36864);
    float* sig  = (float*)(xtp + 65536);

    k_prep_x <<<576,  256, 0, stream>>>(x, xt);
    k_prep_w <<<2304, 256, 0, stream>>>(w_dcn, wt2);
    k_prep_wo<<<162,  256, 0, stream>>>(w_off, w_offp);
    k_off    <<<576,  512, 0, stream>>>(xt, w_offp, b_off, offp);
    k_dcn    <<<576,  512, 0, stream>>>(xt, offp, wt2, b_dcn, y, gsum, gss);
    k_stats  <<<4,    256, 0, stream>>>(gsum, gss, gamma, beta, w2, ab, w2s);
    k_cb     <<<36,    64, 0, stream>>>(ab, w2, cB);
    k_sig    <<<1152, 256, 0, stream>>>(y, w2s, cB, b2, sig);
    k_final  <<<576,  256, 0, stream>>>(y, ab, sig, out);
}